// Round 4
// baseline (207.423 us; speedup 1.0000x reference)
//
#include <hip/hip_runtime.h>
#include <math.h>

#define LRELU(v) ((v) > 0.f ? (v) : 0.2f * (v))

// ---------------------------------------------------------------------------
// K1: h1 = lrelu(x@W1+b1) [1024,256]; h2 = h1@W2+b2 [1024,128]; BN stats.
// 256 blocks x 256 threads, 4 rows per block.
// ---------------------------------------------------------------------------
__global__ __launch_bounds__(256) void k1_mlp12(
    const float* __restrict__ x,
    const float* __restrict__ W1, const float* __restrict__ b1,
    const float* __restrict__ W2, const float* __restrict__ b2,
    float* __restrict__ h2g, float* __restrict__ stats)
{
    __shared__ float xs[4 * 128];
    __shared__ float h1s[4 * 256];
    const int t = threadIdx.x;
    const int r0 = blockIdx.x * 4;

    // stage 4 rows of x (512 floats), coalesced
    for (int p = 0; p < 2; ++p) {
        int idx = t + p * 256;
        xs[idx] = x[r0 * 128 + idx];
    }
    __syncthreads();

    // h1: thread t owns column t for all 4 rows
    {
        float a0 = b1[t], a1 = a0, a2 = a0, a3 = a0;
        for (int k = 0; k < 128; ++k) {
            float w = W1[k * 256 + t];          // coalesced
            a0 += xs[0 * 128 + k] * w;          // LDS broadcast
            a1 += xs[1 * 128 + k] * w;
            a2 += xs[2 * 128 + k] * w;
            a3 += xs[3 * 128 + k] * w;
        }
        h1s[0 * 256 + t] = LRELU(a0);
        h1s[1 * 256 + t] = LRELU(a1);
        h1s[2 * 256 + t] = LRELU(a2);
        h1s[3 * 256 + t] = LRELU(a3);
    }
    __syncthreads();

    // h2: thread t -> col c = t&127, rows rr and rr+2 (rr = t>>7)
    {
        const int c = t & 127;
        const int rr = t >> 7;
        float a0 = b2[c], a1 = a0;
        for (int k = 0; k < 256; ++k) {
            float w = W2[k * 128 + c];          // coalesced (2x reuse)
            a0 += h1s[rr * 256 + k] * w;        // LDS broadcast per wave
            a1 += h1s[(rr + 2) * 256 + k] * w;
        }
        h2g[(r0 + rr) * 128 + c] = a0;
        h2g[(r0 + rr + 2) * 128 + c] = a1;
        atomicAdd(stats + c, a0 + a1);
        atomicAdd(stats + 128 + c, a0 * a0 + a1 * a1);
    }
}

// ---------------------------------------------------------------------------
// K2: BN(train stats)+lrelu -> h3 -> attention (seq_len=1) -> h4 -> M=h4@T2.
// M stored with row stride 256 (250 real cols) so K3 can float4-stage it.
// 256 blocks x 256 threads, 4 rows per block.
// ---------------------------------------------------------------------------
__global__ __launch_bounds__(256) void k2_bn_attn_m(
    const float* __restrict__ h2g, const float* __restrict__ stats,
    const float* __restrict__ gamma, const float* __restrict__ beta,
    const float* __restrict__ W3, const float* __restrict__ b3,
    const float* __restrict__ Wv, const float* __restrict__ bv,
    const float* __restrict__ Wo, const float* __restrict__ bo,
    const float* __restrict__ T2,
    float* __restrict__ h4g, float* __restrict__ Mg)
{
    __shared__ float a[4 * 128];
    __shared__ float h3s[4 * 64];
    __shared__ float vs[4 * 64];
    __shared__ float h4s[4 * 64];
    const int t = threadIdx.x;
    const int r0 = blockIdx.x * 4;

    // BN + lrelu, staged to LDS
    for (int p = 0; p < 2; ++p) {
        int idx = t + p * 256;
        int c = idx & 127;
        float s = stats[c], ss = stats[128 + c];
        float mean = s * (1.f / 1024.f);
        float var = ss * (1.f / 1024.f) - mean * mean;
        float rstd = rsqrtf(var + 1e-5f);
        float v = (h2g[r0 * 128 + idx] - mean) * rstd * gamma[c] + beta[c];
        a[idx] = LRELU(v);
    }
    __syncthreads();

    const int c3 = t & 63, r = t >> 6;
    // h3 = lrelu(a@W3+b3)
    {
        float acc = b3[c3];
        for (int k = 0; k < 128; ++k) acc += a[r * 128 + k] * W3[k * 64 + c3];
        h3s[r * 64 + c3] = LRELU(acc);
    }
    __syncthreads();
    // v = h3@Wv+bv
    {
        float acc = bv[c3];
        for (int k = 0; k < 64; ++k) acc += h3s[r * 64 + k] * Wv[k * 64 + c3];
        vs[r * 64 + c3] = acc;
    }
    __syncthreads();
    // h4 = h3 + v@Wo + bo
    {
        float acc = bo[c3];
        for (int k = 0; k < 64; ++k) acc += vs[r * 64 + k] * Wo[k * 64 + c3];
        float h4 = h3s[r * 64 + c3] + acc;
        h4s[r * 64 + c3] = h4;
        h4g[(r0 + r) * 64 + c3] = h4;
    }
    __syncthreads();
    // M = h4 @ T2  (T2 is T viewed [64,250]); 4x250 outputs
    for (int p = 0; p < 4; ++p) {
        int idx = t + p * 256;
        if (idx < 1000) {
            int rr = idx / 250, c = idx - rr * 250;
            float acc = 0.f;
            for (int k = 0; k < 64; ++k) acc += h4s[rr * 64 + k] * T2[k * 250 + c];
            Mg[(r0 + rr) * 256 + c] = acc;
        }
    }
}

// ---------------------------------------------------------------------------
// K3: all-pairs L1 + exp. Grid = 16 j-tiles x 16 i-chunks = 256 blocks.
// Thread t: j_local = t&63, group g = t>>6 owns c in {g, g+4, ...} (12-13 c's).
// M[j] fragments in registers; M[i] chunks staged in LDS (float4, coalesced).
// All LDS compute reads are wave-uniform addresses -> broadcast, 0 conflicts.
// ---------------------------------------------------------------------------
__global__ __launch_bounds__(256) void k3_pairs(
    const float* __restrict__ Mg, float* __restrict__ opart)
{
    __shared__ float mi[16 * 256];
    const int t = threadIdx.x;
    const int bj = blockIdx.x >> 4;
    const int bi = blockIdx.x & 15;
    const int jl = t & 63, g = t >> 6;
    const int j = bj * 64 + jl;

    float mj[13][5];
    float acc[13];
#pragma unroll
    for (int m = 0; m < 13; ++m) {
        int c = 4 * m + g;
        acc[m] = 0.f;
        if (c < 50) {
#pragma unroll
            for (int k = 0; k < 5; ++k) mj[m][k] = Mg[j * 256 + c * 5 + k];
        }
    }

    const int i0 = bi * 64;
    for (int ch = 0; ch < 4; ++ch) {
        __syncthreads();
        const float4* src = (const float4*)(Mg + (size_t)(i0 + ch * 16) * 256);
        float4* dst = (float4*)mi;
        for (int p = 0; p < 4; ++p) dst[t + p * 256] = src[t + p * 256];
        __syncthreads();
        for (int ii = 0; ii < 16; ++ii) {
            const float* mrow = mi + ii * 256;
#pragma unroll
            for (int m = 0; m < 13; ++m) {
                int c = 4 * m + g;              // g is wave-uniform -> no divergence
                if (c < 50) {
                    float d = fabsf(mrow[c * 5 + 0] - mj[m][0])
                            + fabsf(mrow[c * 5 + 1] - mj[m][1])
                            + fabsf(mrow[c * 5 + 2] - mj[m][2])
                            + fabsf(mrow[c * 5 + 3] - mj[m][3])
                            + fabsf(mrow[c * 5 + 4] - mj[m][4]);
                    acc[m] += __expf(-d);
                }
            }
        }
    }
#pragma unroll
    for (int m = 0; m < 13; ++m) {
        int c = 4 * m + g;
        if (c < 50) opart[(size_t)bi * 51200 + (size_t)j * 50 + c] = acc[m];
    }
}

// ---------------------------------------------------------------------------
// K4: reduce 16 partials, subtract self-term, dot feat=[h4,o] with Ws, +bs.
// One wave (64 threads) per row j.
// ---------------------------------------------------------------------------
__global__ __launch_bounds__(64) void k4_score(
    const float* __restrict__ h4g, const float* __restrict__ opart,
    const float* __restrict__ Ws, const float* __restrict__ bs,
    float* __restrict__ out)
{
    const int j = blockIdx.x, t = threadIdx.x;
    float contrib = h4g[j * 64 + t] * Ws[t];
    if (t < 50) {
        float s = 0.f;
        for (int bi = 0; bi < 16; ++bi)
            s += opart[(size_t)bi * 51200 + (size_t)j * 50 + t];
        contrib += (s - 1.0f) * Ws[64 + t];   // -1 removes self term exp(0)
    }
    for (int off = 32; off > 0; off >>= 1)
        contrib += __shfl_down(contrib, off, 64);
    if (t == 0) out[j] = contrib + bs[0];
}

// ---------------------------------------------------------------------------
// ws layout (float offsets):
//   h2    @ 0       (131072)
//   stats @ 131072  (256: sum[128], sumsq[128])
//   h4    @ 131328  (65536)
//   M     @ 196864  (1024*256, row stride 256, 250 used)
//   opart @ 459008  (16*1024*50)
// total ~5.1 MB
// ---------------------------------------------------------------------------
extern "C" void kernel_launch(void* const* d_in, const int* in_sizes, int n_in,
                              void* d_out, int out_size, void* d_ws, size_t ws_size,
                              hipStream_t stream)
{
    const float* x     = (const float*)d_in[0];
    const float* W1    = (const float*)d_in[1];
    const float* b1    = (const float*)d_in[2];
    const float* W2    = (const float*)d_in[3];
    const float* b2    = (const float*)d_in[4];
    const float* gamma = (const float*)d_in[5];
    const float* beta  = (const float*)d_in[6];
    const float* W3    = (const float*)d_in[7];
    const float* b3    = (const float*)d_in[8];
    const float* Wv    = (const float*)d_in[9];
    const float* bv    = (const float*)d_in[10];
    const float* Wo    = (const float*)d_in[11];
    const float* bo    = (const float*)d_in[12];
    const float* T2    = (const float*)d_in[13];
    const float* Ws    = (const float*)d_in[14];
    const float* bs    = (const float*)d_in[15];

    float* ws    = (float*)d_ws;
    float* h2    = ws + 0;
    float* stats = ws + 131072;
    float* h4    = ws + 131328;
    float* Mg    = ws + 196864;
    float* opart = ws + 459008;
    float* out   = (float*)d_out;

    hipMemsetAsync(stats, 0, 256 * sizeof(float), stream);
    hipLaunchKernelGGL(k1_mlp12, dim3(256), dim3(256), 0, stream,
                       x, W1, b1, W2, b2, h2, stats);
    hipLaunchKernelGGL(k2_bn_attn_m, dim3(256), dim3(256), 0, stream,
                       h2, stats, gamma, beta, W3, b3, Wv, bv, Wo, bo, T2, h4, Mg);
    hipLaunchKernelGGL(k3_pairs, dim3(256), dim3(256), 0, stream, Mg, opart);
    hipLaunchKernelGGL(k4_score, dim3(1024), dim3(64), 0, stream,
                       h4, opart, Ws, bs, out);
}

// Round 5
// 143.910 us; speedup vs baseline: 1.4413x; 1.4413x over previous
//
#include <hip/hip_runtime.h>
#include <math.h>

#define LRELU(v) ((v) > 0.f ? (v) : 0.2f * (v))

// ---------------------------------------------------------------------------
// K1: h1 = lrelu(x@W1+b1) [1024,256]; h2 = h1@W2+b2 [1024,128]; BN stats.
// 512 blocks x 256 threads, 2 rows/block (8 waves/CU vs old 4).
// ---------------------------------------------------------------------------
__global__ __launch_bounds__(256) void k1_mlp12(
    const float* __restrict__ x,
    const float* __restrict__ W1, const float* __restrict__ b1,
    const float* __restrict__ W2, const float* __restrict__ b2,
    float* __restrict__ h2g, float* __restrict__ stats)
{
    __shared__ float xs[256];
    __shared__ float h1s[512];
    __shared__ float ssum[256];
    __shared__ float ssq[256];
    const int t = threadIdx.x;
    const int r0 = blockIdx.x * 2;

    xs[t] = x[r0 * 128 + t];                    // 2 rows of x, coalesced
    __syncthreads();

    // h1: thread t = column, both rows share the W1 load
    {
        float a0 = b1[t], a1 = a0;
        for (int k = 0; k < 128; ++k) {
            float w = W1[k * 256 + t];          // coalesced
            a0 += xs[k] * w;
            a1 += xs[128 + k] * w;
        }
        h1s[t] = LRELU(a0);
        h1s[256 + t] = LRELU(a1);
    }
    __syncthreads();

    // h2: thread (c = t&127, rr = t>>7) -> one output
    {
        const int c = t & 127;
        const int rr = t >> 7;
        float a = b2[c];
        for (int k = 0; k < 256; ++k)
            a += h1s[rr * 256 + k] * W2[k * 128 + c];  // W2 coalesced, L1 serves rr=1
        h2g[(r0 + rr) * 128 + c] = a;
        ssum[t] = a;                            // t == rr*128 + c
        ssq[t] = a * a;
    }
    __syncthreads();
    // one atomic per column per block
    if (t < 128)      atomicAdd(stats + t, ssum[t] + ssum[128 + t]);
    else { int c = t - 128; atomicAdd(stats + 128 + c, ssq[c] + ssq[128 + c]); }
}

// ---------------------------------------------------------------------------
// K2: BN+lrelu -> h3 -> attn(seq=1) -> h4 -> Mt = (h4@T2)^T.
// 1024 blocks x 256 threads, 1 row/block (16 waves/CU).
// Mt layout: [260][1024] col-major (cols 250..259 zero padding) so K3 can
// stage coalesced runs and so ct=12 (c=48..51) reads valid zeros.
// ---------------------------------------------------------------------------
__global__ __launch_bounds__(256) void k2_bn_attn_m(
    const float* __restrict__ h2g, const float* __restrict__ stats,
    const float* __restrict__ gamma, const float* __restrict__ beta,
    const float* __restrict__ W3, const float* __restrict__ b3,
    const float* __restrict__ Wv, const float* __restrict__ bv,
    const float* __restrict__ Wo, const float* __restrict__ bo,
    const float* __restrict__ T2,
    float* __restrict__ h4g, float* __restrict__ Mt)
{
    __shared__ float a[128];
    __shared__ float hp[256];
    __shared__ float h3s[64];
    __shared__ float vs[64];
    __shared__ float h4s[64];
    const int t = threadIdx.x;
    const int r = blockIdx.x;
    const int c3 = t & 63, q = t >> 6;

    // BN (batch stats) + lrelu
    if (t < 128) {
        float s = stats[t], ss = stats[128 + t];
        float mean = s * (1.f / 1024.f);
        float var = ss * (1.f / 1024.f) - mean * mean;
        float rstd = rsqrtf(var + 1e-5f);
        float v = (h2g[r * 128 + t] - mean) * rstd * gamma[t] + beta[t];
        a[t] = LRELU(v);
    }
    __syncthreads();

    // h3 = lrelu(a@W3+b3): 64 outputs, K=128 split 4 ways
    {
        float p = 0.f;
        for (int k = 32 * q; k < 32 * q + 32; ++k) p += a[k] * W3[k * 64 + c3];
        hp[q * 64 + c3] = p;
    }
    __syncthreads();
    if (t < 64) h3s[t] = LRELU(hp[t] + hp[64 + t] + hp[128 + t] + hp[192 + t] + b3[t]);
    __syncthreads();

    // v = h3@Wv+bv: K=64 split 4 ways
    {
        float p = 0.f;
        for (int k = 16 * q; k < 16 * q + 16; ++k) p += h3s[k] * Wv[k * 64 + c3];
        hp[q * 64 + c3] = p;
    }
    __syncthreads();
    if (t < 64) vs[t] = hp[t] + hp[64 + t] + hp[128 + t] + hp[192 + t] + bv[t];
    __syncthreads();

    // h4 = h3 + v@Wo + bo
    {
        float p = 0.f;
        for (int k = 16 * q; k < 16 * q + 16; ++k) p += vs[k] * Wo[k * 64 + c3];
        hp[q * 64 + c3] = p;
    }
    __syncthreads();
    if (t < 64) {
        float h4 = h3s[t] + hp[t] + hp[64 + t] + hp[128 + t] + hp[192 + t] + bo[t];
        h4s[t] = h4;
        h4g[r * 64 + t] = h4;
    }
    __syncthreads();

    // Mt[col][r] = sum_k h4s[k] * T2[k*250+col]; pad cols 250..259 with 0
    if (t < 250) {
        float m = 0.f;
        for (int k = 0; k < 64; ++k) m += h4s[k] * T2[k * 250 + t];  // coalesced
        Mt[(size_t)t * 1024 + r] = m;
    } else {
        Mt[(size_t)t * 1024 + r] = 0.f;
    }
    if (t < 4) Mt[(size_t)(256 + t) * 1024 + r] = 0.f;
}

// ---------------------------------------------------------------------------
// K3: all-pairs L1 + exp. One (j,c) per thread: mj = 5 regs, light VGPR.
// Grid = 16 jt x 13 ct x 8 ic = 1664 blocks (6.5 blocks/CU ~ 26 waves/CU).
// Block stages cols [ct*20, ct*20+20) over its 128-i chunk: 20 coalesced
// 128-dword runs -> LDS (10 KB). Compute reads are wave-uniform broadcasts
// (cl = t>>6 is constant per wave).
// ---------------------------------------------------------------------------
__global__ __launch_bounds__(256) void k3_pairs(
    const float* __restrict__ Mt, float* __restrict__ opart)
{
    __shared__ float mi[2560];                  // [20 cols][128 i]
    const int t = threadIdx.x;
    const int b = blockIdx.x;
    const int jt = b / 104;
    const int rem = b - jt * 104;
    const int ct = rem >> 3;
    const int ic = rem & 7;
    const int jl = t & 63, cl = t >> 6;
    const int j = jt * 64 + jl;
    const int c = ct * 4 + cl;                  // 0..51 (50,51 read zero pad)
    const int i0 = ic * 128;

    // stage: 2560 floats, 10 per thread, coalesced within 128-runs
    for (int qq = 0; qq < 10; ++qq) {
        int idx = qq * 256 + t;
        int cc = idx >> 7, il = idx & 127;
        mi[idx] = Mt[(size_t)(ct * 20 + cc) * 1024 + i0 + il];
    }

    float mj0 = Mt[(size_t)(c * 5 + 0) * 1024 + j];
    float mj1 = Mt[(size_t)(c * 5 + 1) * 1024 + j];
    float mj2 = Mt[(size_t)(c * 5 + 2) * 1024 + j];
    float mj3 = Mt[(size_t)(c * 5 + 3) * 1024 + j];
    float mj4 = Mt[(size_t)(c * 5 + 4) * 1024 + j];
    __syncthreads();

    const float* m0 = mi + (cl * 5 + 0) * 128;
    const float* m1 = mi + (cl * 5 + 1) * 128;
    const float* m2 = mi + (cl * 5 + 2) * 128;
    const float* m3 = mi + (cl * 5 + 3) * 128;
    const float* m4 = mi + (cl * 5 + 4) * 128;

    float acc0 = 0.f, acc1 = 0.f;               // 2 chains to relax add latency
    for (int il = 0; il < 128; il += 2) {
        float d0 = fabsf(m0[il] - mj0) + fabsf(m1[il] - mj1) + fabsf(m2[il] - mj2)
                 + fabsf(m3[il] - mj3) + fabsf(m4[il] - mj4);
        float d1 = fabsf(m0[il+1] - mj0) + fabsf(m1[il+1] - mj1) + fabsf(m2[il+1] - mj2)
                 + fabsf(m3[il+1] - mj3) + fabsf(m4[il+1] - mj4);
        acc0 += __expf(-d0);
        acc1 += __expf(-d1);
    }
    opart[(size_t)(ic * 1024 + j) * 52 + c] = acc0 + acc1;
}

// ---------------------------------------------------------------------------
// K4: reduce 8 partials, subtract self-term, dot feat=[h4,o] with Ws, +bs.
// One wave per row j.
// ---------------------------------------------------------------------------
__global__ __launch_bounds__(64) void k4_score(
    const float* __restrict__ h4g, const float* __restrict__ opart,
    const float* __restrict__ Ws, const float* __restrict__ bs,
    float* __restrict__ out)
{
    const int j = blockIdx.x, t = threadIdx.x;
    float contrib = h4g[j * 64 + t] * Ws[t];
    if (t < 50) {
        float s = 0.f;
        for (int ic = 0; ic < 8; ++ic)
            s += opart[(size_t)(ic * 1024 + j) * 52 + t];
        contrib += (s - 1.0f) * Ws[64 + t];     // -1 removes self term exp(0)
    }
    for (int off = 32; off > 0; off >>= 1)
        contrib += __shfl_down(contrib, off, 64);
    if (t == 0) out[j] = contrib + bs[0];
}

// ---------------------------------------------------------------------------
// ws layout (float offsets):
//   h2    @ 0       (131072)
//   stats @ 131072  (256)
//   h4    @ 131328  (65536)
//   Mt    @ 196864  (260*1024 = 266240, col-major transpose of M)
//   opart @ 463104  (8*1024*52 = 425984)
// total 889088 floats ~ 3.56 MB
// ---------------------------------------------------------------------------
extern "C" void kernel_launch(void* const* d_in, const int* in_sizes, int n_in,
                              void* d_out, int out_size, void* d_ws, size_t ws_size,
                              hipStream_t stream)
{
    const float* x     = (const float*)d_in[0];
    const float* W1    = (const float*)d_in[1];
    const float* b1    = (const float*)d_in[2];
    const float* W2    = (const float*)d_in[3];
    const float* b2    = (const float*)d_in[4];
    const float* gamma = (const float*)d_in[5];
    const float* beta  = (const float*)d_in[6];
    const float* W3    = (const float*)d_in[7];
    const float* b3    = (const float*)d_in[8];
    const float* Wv    = (const float*)d_in[9];
    const float* bv    = (const float*)d_in[10];
    const float* Wo    = (const float*)d_in[11];
    const float* bo    = (const float*)d_in[12];
    const float* T2    = (const float*)d_in[13];
    const float* Ws    = (const float*)d_in[14];
    const float* bs    = (const float*)d_in[15];

    float* ws    = (float*)d_ws;
    float* h2    = ws + 0;
    float* stats = ws + 131072;
    float* h4    = ws + 131328;
    float* Mt    = ws + 196864;
    float* opart = ws + 463104;
    float* out   = (float*)d_out;

    hipMemsetAsync(stats, 0, 256 * sizeof(float), stream);
    hipLaunchKernelGGL(k1_mlp12, dim3(512), dim3(256), 0, stream,
                       x, W1, b1, W2, b2, h2, stats);
    hipLaunchKernelGGL(k2_bn_attn_m, dim3(1024), dim3(256), 0, stream,
                       h2, stats, gamma, beta, W3, b3, Wv, bv, Wo, bo, T2, h4, Mt);
    hipLaunchKernelGGL(k3_pairs, dim3(1664), dim3(256), 0, stream, Mt, opart);
    hipLaunchKernelGGL(k4_score, dim3(1024), dim3(64), 0, stream,
                       h4, opart, Ws, bs, out);
}

// Round 6
// 141.195 us; speedup vs baseline: 1.4691x; 1.0192x over previous
//
#include <hip/hip_runtime.h>
#include <math.h>

#define LRELU(v) ((v) > 0.f ? (v) : 0.2f * (v))

// ---------------------------------------------------------------------------
// K1: h1 = lrelu(x@W1+b1) [1024,256]; h2 = h1@W2+b2 [1024,128]; BN stats.
// 512 blocks x 256 threads, 2 rows/block.
// ---------------------------------------------------------------------------
__global__ __launch_bounds__(256) void k1_mlp12(
    const float* __restrict__ x,
    const float* __restrict__ W1, const float* __restrict__ b1,
    const float* __restrict__ W2, const float* __restrict__ b2,
    float* __restrict__ h2g, float* __restrict__ stats)
{
    __shared__ float xs[256];
    __shared__ float h1s[512];
    __shared__ float ssum[256];
    __shared__ float ssq[256];
    const int t = threadIdx.x;
    const int r0 = blockIdx.x * 2;

    xs[t] = x[r0 * 128 + t];                    // 2 rows of x, coalesced
    __syncthreads();

    // h1: thread t = column, both rows share the W1 load
    {
        float a0 = b1[t], a1 = a0;
        for (int k = 0; k < 128; ++k) {
            float w = W1[k * 256 + t];          // coalesced
            a0 += xs[k] * w;
            a1 += xs[128 + k] * w;
        }
        h1s[t] = LRELU(a0);
        h1s[256 + t] = LRELU(a1);
    }
    __syncthreads();

    // h2: thread (c = t&127, rr = t>>7) -> one output
    {
        const int c = t & 127;
        const int rr = t >> 7;
        float a = b2[c];
        for (int k = 0; k < 256; ++k)
            a += h1s[rr * 256 + k] * W2[k * 128 + c];
        h2g[(r0 + rr) * 128 + c] = a;
        ssum[t] = a;                            // t == rr*128 + c
        ssq[t] = a * a;
    }
    __syncthreads();
    if (t < 128)      atomicAdd(stats + t, ssum[t] + ssum[128 + t]);
    else { int c = t - 128; atomicAdd(stats + 128 + c, ssq[c] + ssq[128 + c]); }
}

// ---------------------------------------------------------------------------
// K2: BN+lrelu -> h3 -> attn(seq=1) -> h4 -> Mt = (h4@T2)^T.
// 512 blocks x 256 threads, 2 rows/block. Only 3 barriers, full-dot phases.
// T2 column loads feed BOTH rows (traffic 33 MB). Mt[260][1024] col-major,
// cols 250..259 zeroed so K3's ct=12 wave reads valid zeros.
// ---------------------------------------------------------------------------
__global__ __launch_bounds__(256) void k2_bn_attn_m(
    const float* __restrict__ h2g, const float* __restrict__ stats,
    const float* __restrict__ gamma, const float* __restrict__ beta,
    const float* __restrict__ W3, const float* __restrict__ b3,
    const float* __restrict__ Wv, const float* __restrict__ bv,
    const float* __restrict__ Wo, const float* __restrict__ bo,
    const float* __restrict__ T2,
    float* __restrict__ h4g, float* __restrict__ Mt)
{
    __shared__ float a[256];                    // [2 rows][128]
    __shared__ float h3s[128];                  // [2][64]
    __shared__ float vss[128];
    __shared__ float h4s[128];
    const int t = threadIdx.x;
    const int r0 = blockIdx.x * 2;

    // BN (batch stats) + lrelu: t = rr*128 + c
    {
        const int c = t & 127;
        float s = stats[c], ss = stats[128 + c];
        float mean = s * (1.f / 1024.f);
        float var = ss * (1.f / 1024.f) - mean * mean;
        float rstd = rsqrtf(var + 1e-5f);
        float v = (h2g[r0 * 128 + t] - mean) * rstd * gamma[c] + beta[c];
        a[t] = LRELU(v);
    }
    __syncthreads();

    const int row = t >> 6, col = t & 63;       // valid for t < 128
    // h3 = lrelu(a@W3+b3)
    if (t < 128) {
        float acc = b3[col];
        for (int k = 0; k < 128; ++k) acc += a[row * 128 + k] * W3[k * 64 + col];
        h3s[row * 64 + col] = LRELU(acc);
    }
    __syncthreads();
    // v = h3@Wv+bv ; then h4 = h3 + v@Wo + bo (v needs only own row: one sync)
    if (t < 128) {
        float acc = bv[col];
        for (int k = 0; k < 64; ++k) acc += h3s[row * 64 + k] * Wv[k * 64 + col];
        vss[row * 64 + col] = acc;
    }
    __syncthreads();
    if (t < 128) {
        float acc = bo[col];
        for (int k = 0; k < 64; ++k) acc += vss[row * 64 + k] * Wo[k * 64 + col];
        float h4 = h3s[row * 64 + col] + acc;
        h4s[row * 64 + col] = h4;
        h4g[(r0 + row) * 64 + col] = h4;
    }
    __syncthreads();

    // Mt[col][r0 / r0+1]: each T2 load feeds both rows
    if (t < 250) {
        float m0 = 0.f, m1 = 0.f;
        for (int k = 0; k < 64; ++k) {
            float w = T2[k * 250 + t];          // coalesced across t
            m0 += h4s[k] * w;
            m1 += h4s[64 + k] * w;
        }
        Mt[(size_t)t * 1024 + r0]     = m0;
        Mt[(size_t)t * 1024 + r0 + 1] = m1;
    } else {
        Mt[(size_t)t * 1024 + r0]     = 0.f;
        Mt[(size_t)t * 1024 + r0 + 1] = 0.f;
    }
    if (t < 4) {
        Mt[(size_t)(256 + t) * 1024 + r0]     = 0.f;
        Mt[(size_t)(256 + t) * 1024 + r0 + 1] = 0.f;
    }
}

// ---------------------------------------------------------------------------
// K3: all-pairs L1 + exp. One (j,c) per thread.
// Grid = 16 jt x 13 ct x 8 ic = 1664 blocks (~26 waves/CU).
// LDS reads are wave-uniform broadcasts; float2 reads halve ds_read count.
// ---------------------------------------------------------------------------
__global__ __launch_bounds__(256) void k3_pairs(
    const float* __restrict__ Mt, float* __restrict__ opart)
{
    __shared__ float mi[2560];                  // [20 cols][128 i]
    const int t = threadIdx.x;
    const int b = blockIdx.x;
    const int jt = b / 104;
    const int rem = b - jt * 104;
    const int ct = rem >> 3;
    const int ic = rem & 7;
    const int jl = t & 63, cl = t >> 6;
    const int j = jt * 64 + jl;
    const int c = ct * 4 + cl;                  // 0..51 (50,51 read zero pad)
    const int i0 = ic * 128;

    for (int qq = 0; qq < 10; ++qq) {
        int idx = qq * 256 + t;
        int cc = idx >> 7, il = idx & 127;
        mi[idx] = Mt[(size_t)(ct * 20 + cc) * 1024 + i0 + il];
    }

    float mj0 = Mt[(size_t)(c * 5 + 0) * 1024 + j];
    float mj1 = Mt[(size_t)(c * 5 + 1) * 1024 + j];
    float mj2 = Mt[(size_t)(c * 5 + 2) * 1024 + j];
    float mj3 = Mt[(size_t)(c * 5 + 3) * 1024 + j];
    float mj4 = Mt[(size_t)(c * 5 + 4) * 1024 + j];
    __syncthreads();

    const float2* m0 = (const float2*)(mi + (cl * 5 + 0) * 128);
    const float2* m1 = (const float2*)(mi + (cl * 5 + 1) * 128);
    const float2* m2 = (const float2*)(mi + (cl * 5 + 2) * 128);
    const float2* m3 = (const float2*)(mi + (cl * 5 + 3) * 128);
    const float2* m4 = (const float2*)(mi + (cl * 5 + 4) * 128);

    float acc0 = 0.f, acc1 = 0.f;
    for (int p = 0; p < 64; ++p) {
        float2 v0 = m0[p], v1 = m1[p], v2 = m2[p], v3 = m3[p], v4 = m4[p];
        float d0 = fabsf(v0.x - mj0) + fabsf(v1.x - mj1) + fabsf(v2.x - mj2)
                 + fabsf(v3.x - mj3) + fabsf(v4.x - mj4);
        float d1 = fabsf(v0.y - mj0) + fabsf(v1.y - mj1) + fabsf(v2.y - mj2)
                 + fabsf(v3.y - mj3) + fabsf(v4.y - mj4);
        acc0 += __expf(-d0);
        acc1 += __expf(-d1);
    }
    opart[(size_t)(ic * 1024 + j) * 52 + c] = acc0 + acc1;
}

// ---------------------------------------------------------------------------
// K4: reduce 8 partials, subtract self-term, dot feat=[h4,o] with Ws, +bs.
// ---------------------------------------------------------------------------
__global__ __launch_bounds__(64) void k4_score(
    const float* __restrict__ h4g, const float* __restrict__ opart,
    const float* __restrict__ Ws, const float* __restrict__ bs,
    float* __restrict__ out)
{
    const int j = blockIdx.x, t = threadIdx.x;
    float contrib = h4g[j * 64 + t] * Ws[t];
    if (t < 50) {
        float s = 0.f;
        for (int ic = 0; ic < 8; ++ic)
            s += opart[(size_t)(ic * 1024 + j) * 52 + t];
        contrib += (s - 1.0f) * Ws[64 + t];     // -1 removes self term exp(0)
    }
    for (int off = 32; off > 0; off >>= 1)
        contrib += __shfl_down(contrib, off, 64);
    if (t == 0) out[j] = contrib + bs[0];
}

// ---------------------------------------------------------------------------
// ws layout (float offsets):
//   h2    @ 0       (131072)
//   stats @ 131072  (256)
//   h4    @ 131328  (65536)
//   Mt    @ 196864  (260*1024 = 266240, col-major transpose of M)
//   opart @ 463104  (8*1024*52 = 425984)
// ---------------------------------------------------------------------------
extern "C" void kernel_launch(void* const* d_in, const int* in_sizes, int n_in,
                              void* d_out, int out_size, void* d_ws, size_t ws_size,
                              hipStream_t stream)
{
    const float* x     = (const float*)d_in[0];
    const float* W1    = (const float*)d_in[1];
    const float* b1    = (const float*)d_in[2];
    const float* W2    = (const float*)d_in[3];
    const float* b2    = (const float*)d_in[4];
    const float* gamma = (const float*)d_in[5];
    const float* beta  = (const float*)d_in[6];
    const float* W3    = (const float*)d_in[7];
    const float* b3    = (const float*)d_in[8];
    const float* Wv    = (const float*)d_in[9];
    const float* bv    = (const float*)d_in[10];
    const float* Wo    = (const float*)d_in[11];
    const float* bo    = (const float*)d_in[12];
    const float* T2    = (const float*)d_in[13];
    const float* Ws    = (const float*)d_in[14];
    const float* bs    = (const float*)d_in[15];

    float* ws    = (float*)d_ws;
    float* h2    = ws + 0;
    float* stats = ws + 131072;
    float* h4    = ws + 131328;
    float* Mt    = ws + 196864;
    float* opart = ws + 463104;
    float* out   = (float*)d_out;

    hipMemsetAsync(stats, 0, 256 * sizeof(float), stream);
    hipLaunchKernelGGL(k1_mlp12, dim3(512), dim3(256), 0, stream,
                       x, W1, b1, W2, b2, h2, stats);
    hipLaunchKernelGGL(k2_bn_attn_m, dim3(512), dim3(256), 0, stream,
                       h2, stats, gamma, beta, W3, b3, Wv, bv, Wo, bo, T2, h4, Mt);
    hipLaunchKernelGGL(k3_pairs, dim3(1664), dim3(256), 0, stream, Mt, opart);
    hipLaunchKernelGGL(k4_score, dim3(1024), dim3(64), 0, stream,
                       h4, opart, Ws, bs, out);
}